// Round 15
// baseline (441.075 us; speedup 1.0000x reference)
//
#include <hip/hip_runtime.h>
#include <hip/hip_bf16.h>
#include <float.h>
#include <math.h>

#define KEY_DIM   512
#define VALUE_DIM 128
#define CAPACITY  500000
#define NRET      16

#define NBLKS     1536                     // 6 blocks/CU resident
#define NWAVES    (NBLKS * 4)              // 6144
#define BATCH     8                        // rows per wave-batch
#define SWEEPR    (NWAVES * BATCH)         // 49152 rows per sweep
#define NSWEEPS   10                       // 491520 rows uniform
#define TAILW     ((CAPACITY - NSWEEPS * SWEEPR) / BATCH)   // 1060 tail waves

__device__ __forceinline__ float wave_sum(float x) {
#pragma unroll
    for (int s = 32; s > 0; s >>= 1) x += __shfl_xor(x, s);
    return x;
}

// ---------------- Kernel 1a/1b: y[r] = act(dot(W[r,:], x) + b[r]) ----------
template <bool SILU>
__global__ __launch_bounds__(256) void matvec512(
        const float* __restrict__ W, const float* __restrict__ x,
        const float* __restrict__ b, float* __restrict__ y) {
    const int wid  = threadIdx.x >> 6;
    const int lane = threadIdx.x & 63;
    const int r = blockIdx.x * 4 + wid;          // 0..511

    const float4* Wr = (const float4*)(W + (size_t)r * KEY_DIM);
    const float4* xv = (const float4*)x;

    float4 w0 = Wr[lane], w1 = Wr[lane + 64];
    float4 x0 = xv[lane], x1 = xv[lane + 64];

    float dot = w0.x * x0.x + w0.y * x0.y + w0.z * x0.z + w0.w * x0.w
              + w1.x * x1.x + w1.y * x1.y + w1.z * x1.z + w1.w * x1.w;
    dot = wave_sum(dot);

    if (lane == 0) {
        float v = dot + b[r];
        if (SILU) v = v / (1.0f + expf(-v));     // silu = x*sigmoid(x)
        y[r] = v;
    }
}

// ---------------- Kernel 1c: LayerNorm + l2-normalize -> qn[512] -----------
__global__ __launch_bounds__(512) void ln_l2norm(
        const float* __restrict__ h, const float* __restrict__ gamma,
        const float* __restrict__ beta, float* __restrict__ qn) {
    __shared__ float s1[8], s2[8];
    const int t = threadIdx.x;                   // 512 threads = 8 waves
    const int wid = t >> 6, lane = t & 63;

    float x = h[t];
    float a = x, bb = x * x;
#pragma unroll
    for (int s = 32; s > 0; s >>= 1) { a += __shfl_xor(a, s); bb += __shfl_xor(bb, s); }
    if (lane == 0) { s1[wid] = a; s2[wid] = bb; }
    __syncthreads();

    float suma = 0.f, sumb = 0.f;
#pragma unroll
    for (int i = 0; i < 8; ++i) { suma += s1[i]; sumb += s2[i]; }
    float mu  = suma * (1.0f / KEY_DIM);
    float var = sumb * (1.0f / KEY_DIM) - mu * mu;      // biased, like torch LN
    float ln  = (x - mu) / sqrtf(var + 1e-5f) * gamma[t] + beta[t];

    float c = wave_sum(ln * ln);
    __syncthreads();
    if (lane == 0) s1[wid] = c;
    __syncthreads();
    float ss = 0.f;
#pragma unroll
    for (int i = 0; i < 8; ++i) ss += s1[i];
    float n = fmaxf(sqrtf(ss), 1e-12f);
    qn[t] = ln / n;
}

// ---------------- Kernel 2: coalesced sim, LDS-transpose reduce ------------
// The one untested cell of the structure matrix: coalesced loads (R2's
// pattern, 16 x 1KB instructions per 8-row batch) + near-zero serial chain
// (per-lane partials -> wave-private padded LDS slab -> transposed strided
// re-read -> 3-stage 8-lane shuffle; ~5 deps vs R2's ~12) + 24 waves/CU
// (launch_bounds(256,6), 16.5 KB LDS) + NO inline asm (compiler schedules,
// TLP hides latency -- the copy-bench configuration).
__global__ __launch_bounds__(256, 6) void sim_topk(
        const float* __restrict__ keys, const float* __restrict__ qn,
        float* __restrict__ cand_v, int* __restrict__ cand_i) {
    __shared__ float2 pdps[4][BATCH][66];        // +2 pad: row stride 528B
    __shared__ float bv[64];
    __shared__ int   bi[64];

    const int tid  = threadIdx.x;
    const int w    = tid >> 6;
    const int lane = tid & 63;
    const int gw   = blockIdx.x * 4 + w;         // 0..6143

    const float4* q4 = (const float4*)qn;
    float4 q0 = q4[lane], q1 = q4[lane + 64];

    // wave-uniform top-16
    float v[16]; int id[16];
#pragma unroll
    for (int j = 0; j < 16; ++j) { v[j] = -FLT_MAX; id[j] = 0x7fffffff; }

    auto batch = [&](int base) {
        // coalesced loads + per-lane partials (no cross-lane yet)
        float2 acc[BATCH];
#pragma unroll
        for (int r = 0; r < BATCH; ++r) {
            const float4* krow = (const float4*)(keys + (size_t)(base + r) * KEY_DIM);
            float4 k0 = krow[lane], k1 = krow[lane + 64];
            float d = k0.x * q0.x + k0.y * q0.y + k0.z * q0.z + k0.w * q0.w
                    + k1.x * q1.x + k1.y * q1.y + k1.z * q1.z + k1.w * q1.w;
            float s = k0.x * k0.x + k0.y * k0.y + k0.z * k0.z + k0.w * k0.w
                    + k1.x * k1.x + k1.y * k1.y + k1.z * k1.z + k1.w * k1.w;
            acc[r].x = d; acc[r].y = s;
        }
        // wave-private LDS slab (no barrier; compiler orders same-wave ds ops)
#pragma unroll
        for (int r = 0; r < BATCH; ++r) pdps[w][r][lane] = acc[r];
        // transposed re-read: lane handles row lane>>3, sums 8 strided entries
        float2 t; t.x = 0.f; t.y = 0.f;
        const int row8 = lane >> 3, off8 = lane & 7;
#pragma unroll
        for (int k = 0; k < 8; ++k) {
            float2 p = pdps[w][row8][off8 + 8 * k];
            t.x += p.x; t.y += p.y;
        }
#pragma unroll
        for (int st = 1; st <= 4; st <<= 1) {    // 3-stage reduce in 8-lane group
            t.x += __shfl_xor(t.x, st);
            t.y += __shfl_xor(t.y, st);
        }
        float sim = t.x / fmaxf(sqrtf(t.y), 1e-12f);   // lanes 8r..8r+7: row r
#pragma unroll
        for (int r = 0; r < BATCH; ++r) {
            float sq = __shfl(sim, r * 8);       // wave-uniform
            if (sq > v[15]) {
                float cv = sq; int ci = base + r;
#pragma unroll
                for (int jj = 0; jj < 16; ++jj) {
                    if (cv > v[jj]) {
                        float tv = v[jj]; int ti = id[jj];
                        v[jj] = cv; id[jj] = ci; cv = tv; ci = ti;
                    }
                }
            }
        }
    };

#pragma unroll 1
    for (int s = 0; s < NSWEEPS; ++s)
        batch(gw * BATCH + s * SWEEPR);
    if (gw < TAILW)
        batch(NSWEEPS * SWEEPR + gw * BATCH);    // tail: 8480 rows

    // ---- merge 4 waves' top-16 -> block top-16 ----------------------------
    if (lane == 0) {
#pragma unroll
        for (int j = 0; j < 16; ++j) { bv[w * 16 + j] = v[j]; bi[w * 16 + j] = id[j]; }
    }
    __syncthreads();
    if (w == 0) {
        float lv = bv[lane]; int li = bi[lane];
        for (int rr = 0; rr < NRET; ++rr) {
            float mv = lv; int mi = li;
#pragma unroll
            for (int s = 32; s > 0; s >>= 1) {
                float ov = __shfl_xor(mv, s); int oi = __shfl_xor(mi, s);
                if (ov > mv || (ov == mv && oi < mi)) { mv = ov; mi = oi; }
            }
            if (lane == 0) {
                cand_v[blockIdx.x * NRET + rr] = mv;
                cand_i[blockIdx.x * NRET + rr] = mi;
            }
            if (lv == mv && li == mi) { lv = -FLT_MAX; li = 0x7fffffff; }
        }
    }
}

// ---------------- Kernel 3: final top-16 + softmax + gather ----------------
__global__ __launch_bounds__(256) void merge_out(
        const float* __restrict__ cand_v, const int* __restrict__ cand_i,
        const float* __restrict__ values, float* __restrict__ out) {
    const int tid  = threadIdx.x;
    const int wid  = tid >> 6;
    const int lane = tid & 63;
    const int M4 = (NBLKS * NRET) / 4;           // 6144 float4 groups

    float v[16]; int id[16];
#pragma unroll
    for (int j = 0; j < 16; ++j) { v[j] = -FLT_MAX; id[j] = 0x7fffffff; }

    const float4* cv4 = (const float4*)cand_v;
    const int4*   ci4 = (const int4*)cand_i;
    for (int c = tid; c < M4; c += 256) {        // 24 iterations
        float4 cv = cv4[c]; int4 ci = ci4[c];
        float cvs[4] = {cv.x, cv.y, cv.z, cv.w};
        int   cis[4] = {ci.x, ci.y, ci.z, ci.w};
#pragma unroll
        for (int u = 0; u < 4; ++u) {
            float cu = cvs[u]; int iu = cis[u];
            if (cu > v[15]) {
#pragma unroll
                for (int j = 0; j < 16; ++j) {
                    if (cu > v[j]) {
                        float tv = v[j]; int ti = id[j];
                        v[j] = cu; id[j] = iu; cu = tv; iu = ti;
                    }
                }
            }
        }
    }

    __shared__ float sv[64];
    __shared__ int   si[64];
    for (int rr = 0; rr < NRET; ++rr) {
        float mv = v[0]; int mi = id[0];
#pragma unroll
        for (int s = 32; s > 0; s >>= 1) {
            float ov = __shfl_xor(mv, s); int oi = __shfl_xor(mi, s);
            if (ov > mv || (ov == mv && oi < mi)) { mv = ov; mi = oi; }
        }
        if (v[0] == mv && id[0] == mi) {
#pragma unroll
            for (int j = 0; j < 15; ++j) { v[j] = v[j + 1]; id[j] = id[j + 1]; }
            v[15] = -FLT_MAX; id[15] = 0x7fffffff;
        }
        if (lane == 0) { sv[wid * 16 + rr] = mv; si[wid * 16 + rr] = mi; }
    }
    __syncthreads();

    if (wid == 0) {
        float lv = sv[lane]; int li = si[lane];
        float sel_v = -FLT_MAX; int sel_i = 0;
        for (int rr = 0; rr < NRET; ++rr) {
            float mv = lv; int mi = li;
#pragma unroll
            for (int s = 32; s > 0; s >>= 1) {
                float ov = __shfl_xor(mv, s); int oi = __shfl_xor(mi, s);
                if (ov > mv || (ov == mv && oi < mi)) { mv = ov; mi = oi; }
            }
            if (lv == mv && li == mi) { lv = -FLT_MAX; li = 0x7fffffff; }
            if (lane == rr) { sel_v = mv; sel_i = mi; }
        }

        // softmax over the 16 (lane 0 holds the max: rounds are descending)
        float m0 = __shfl(sel_v, 0);
        float e = (lane < NRET) ? expf(sel_v - m0) : 0.0f;
        float denom = wave_sum(e);

        float acc0 = 0.f, acc1 = 0.f;
        for (int rr = 0; rr < NRET; ++rr) {
            float ar = __shfl(e, rr) / denom;
            int   ir = __shfl(sel_i, rr);
            const float* vr = values + (size_t)ir * VALUE_DIM;
            acc0 += ar * vr[lane];
            acc1 += ar * vr[lane + 64];
        }
        out[lane]      = acc0;
        out[lane + 64] = acc1;
    }
}

extern "C" void kernel_launch(void* const* d_in, const int* in_sizes, int n_in,
                              void* d_out, int out_size, void* d_ws, size_t ws_size,
                              hipStream_t stream) {
    const float* query  = (const float*)d_in[0];
    const float* W1     = (const float*)d_in[1];
    const float* b1     = (const float*)d_in[2];
    const float* W2     = (const float*)d_in[3];
    const float* b2     = (const float*)d_in[4];
    const float* gamma  = (const float*)d_in[5];
    const float* beta   = (const float*)d_in[6];
    const float* keys   = (const float*)d_in[7];
    const float* values = (const float*)d_in[8];
    float* out = (float*)d_out;

    float* ws = (float*)d_ws;
    float* h1     = ws;                  // 512
    float* h2     = ws + 512;            // 512
    float* qn     = ws + 1024;           // 512
    float* cand_v = ws + 2048;           // NBLKS*16 floats
    int*   cand_i = (int*)(ws + 2048 + NBLKS * NRET);

    matvec512<true ><<<128, 256, 0, stream>>>(W1, query, b1, h1);
    matvec512<false><<<128, 256, 0, stream>>>(W2, h1, b2, h2);
    ln_l2norm<<<1, 512, 0, stream>>>(h2, gamma, beta, qn);
    sim_topk<<<NBLKS, 256, 0, stream>>>(keys, qn, cand_v, cand_i);
    merge_out<<<1, 256, 0, stream>>>(cand_v, cand_i, values, out);
}

// Round 16
// 262.009 us; speedup vs baseline: 1.6834x; 1.6834x over previous
//
#include <hip/hip_runtime.h>
#include <hip/hip_bf16.h>
#include <float.h>
#include <math.h>

#define KEY_DIM   512
#define VALUE_DIM 128
#define CAPACITY  500000
#define NRET      16

#define SUBROWS   8                        // rows per block sub-tile (4 waves x 2)
#define NBLKS     512                      // 2 blocks/CU, all resident
#define NSUB      (CAPACITY / SUBROWS)     // 62500 sub-tiles
#define RING      4                        // wave-private ring depth

#define AS3 __attribute__((address_space(3)))
#define AS1 __attribute__((address_space(1)))

__device__ __forceinline__ float wave_sum(float x) {
#pragma unroll
    for (int s = 32; s > 0; s >>= 1) x += __shfl_xor(x, s);
    return x;
}

// ---------------- Kernel 1a/1b: y[r] = act(dot(W[r,:], x) + b[r]) ----------
template <bool SILU>
__global__ __launch_bounds__(256) void matvec512(
        const float* __restrict__ W, const float* __restrict__ x,
        const float* __restrict__ b, float* __restrict__ y) {
    const int wid  = threadIdx.x >> 6;
    const int lane = threadIdx.x & 63;
    const int r = blockIdx.x * 4 + wid;          // 0..511

    const float4* Wr = (const float4*)(W + (size_t)r * KEY_DIM);
    const float4* xv = (const float4*)x;

    float4 w0 = Wr[lane], w1 = Wr[lane + 64];
    float4 x0 = xv[lane], x1 = xv[lane + 64];

    float dot = w0.x * x0.x + w0.y * x0.y + w0.z * x0.z + w0.w * x0.w
              + w1.x * x1.x + w1.y * x1.y + w1.z * x1.z + w1.w * x1.w;
    dot = wave_sum(dot);

    if (lane == 0) {
        float v = dot + b[r];
        if (SILU) v = v / (1.0f + expf(-v));     // silu = x*sigmoid(x)
        y[r] = v;
    }
}

// ---------------- Kernel 1c: LayerNorm + l2-normalize -> qn[512] -----------
__global__ __launch_bounds__(512) void ln_l2norm(
        const float* __restrict__ h, const float* __restrict__ gamma,
        const float* __restrict__ beta, float* __restrict__ qn) {
    __shared__ float s1[8], s2[8];
    const int t = threadIdx.x;                   // 512 threads = 8 waves
    const int wid = t >> 6, lane = t & 63;

    float x = h[t];
    float a = x, bb = x * x;
#pragma unroll
    for (int s = 32; s > 0; s >>= 1) { a += __shfl_xor(a, s); bb += __shfl_xor(bb, s); }
    if (lane == 0) { s1[wid] = a; s2[wid] = bb; }
    __syncthreads();

    float suma = 0.f, sumb = 0.f;
#pragma unroll
    for (int i = 0; i < 8; ++i) { suma += s1[i]; sumb += s2[i]; }
    float mu  = suma * (1.0f / KEY_DIM);
    float var = sumb * (1.0f / KEY_DIM) - mu * mu;      // biased, like torch LN
    float ln  = (x - mu) / sqrtf(var + 1e-5f) * gamma[t] + beta[t];

    float c = wave_sum(ln * ln);
    __syncthreads();
    if (lane == 0) s1[wid] = c;
    __syncthreads();
    float ss = 0.f;
#pragma unroll
    for (int i = 0; i < 8; ++i) ss += s1[i];
    float n = fmaxf(sqrtf(ss), 1e-12f);
    qn[t] = ln / n;
}

// ---------------- Kernel 2: ring-pipelined LDS-staged cosine sim -----------
// Best measured structure (R9, 263 µs): wave-private ring of 4 sub-buffers
// (4 KB = wave's 2 rows each): stage(s+3) -> vmcnt(12) [sub s landed; 3 subs
// = 12 KB/wave in flight] -> compute(s). No barriers in the loop; waits are
// wave-local inline asm with a CONSTANT outstanding count (wrap-staging keeps
// the last iterations uniform). Blocks start staggered at (bid*7919) % ns.
// Bank spread: physical 16B-slot p of a row holds logical cell
// L(p) = 4g + ((s-(g>>1))&3), g=p>>2, s=p&3 (SOURCE-side permutation);
// lane m reads logical cells 4m+j at physical 4m+((j+(m>>1))&3); qr[j] static.
__global__ __launch_bounds__(256) void sim_topk(
        const float* __restrict__ keys, const float* __restrict__ qn,
        float* __restrict__ cand_v, int* __restrict__ cand_i) {
    __shared__ float kl[RING][SUBROWS][KEY_DIM];     // 64 KB
    __shared__ float bv[64];
    __shared__ int   bi[64];

    const int tid  = threadIdx.x;
    const int w    = tid >> 6;
    const int lane = tid & 63;
    const int m    = lane & 31;                      // col-slice within row
    const int rsel = lane >> 5;                      // which of wave's 2 rows
    const int bid  = blockIdx.x;
    const int ns   = (NSUB - bid + NBLKS - 1) / NBLKS;   // 122 or 123
    const int s0   = (int)(((unsigned)bid * 7919u) % (unsigned)ns);

    // q fragment: logical cells 4m..4m+3 (16 floats)
    float4 qr[4];
    {
        const float4* q4 = (const float4*)qn;
#pragma unroll
        for (int j = 0; j < 4; ++j) qr[j] = q4[4 * m + j];
    }

    // source byte offsets (within a row) for the two 1KB halves
    int srcoff0, srcoff1;
    {
        int p0 = lane,      g0 = p0 >> 2, sl0 = p0 & 3;
        int p1 = 64 + lane, g1 = p1 >> 2, sl1 = p1 & 3;
        srcoff0 = (4 * g0 + ((sl0 - (g0 >> 1)) & 3)) * 16;
        srcoff1 = (4 * g1 + ((sl1 - (g1 >> 1)) & 3)) * 16;
    }
    // read byte offsets within own row for j=0..3
    int roff[4];
#pragma unroll
    for (int j = 0; j < 4; ++j) roff[j] = (4 * m + ((j + (m >> 1)) & 3)) * 16;

    // wave-uniform top-16
    float v[16]; int id[16];
#pragma unroll
    for (int j = 0; j < 16; ++j) { v[j] = -FLT_MAX; id[j] = 0x7fffffff; }

    // ---- stage: wave w stages rows 2w,2w+1 of global sub G into ring slot --
    auto stage = [&](int G, int slot) {
#pragma unroll
        for (int i = 0; i < 4; ++i) {
            const int rl = 2 * w + (i >> 1);
            const int h  = i & 1;
            const char* gp = (const char*)(keys + ((size_t)G * SUBROWS + rl) * KEY_DIM)
                             + (h ? srcoff1 : srcoff0);
            float* lp = &kl[slot][rl][h * 256];      // wave-uniform base
            __builtin_amdgcn_global_load_lds((const AS1 float*)gp, (AS3 float*)lp,
                                             16, 0, 0);
        }
    };

    // ---- compute: wave processes its 2 rows of ring slot ------------------
    auto compute = [&](int G, int slot) {
        const char* rowbase = (const char*)&kl[slot][2 * w + rsel][0];
        float dot = 0.f, ss = 0.f;
#pragma unroll
        for (int j = 0; j < 4; ++j) {
            float4 k = *(const float4*)(rowbase + roff[j]);
            float4 q = qr[j];
            dot += k.x * q.x + k.y * q.y + k.z * q.z + k.w * q.w;
            ss  += k.x * k.x + k.y * k.y + k.z * k.z + k.w * k.w;
        }
#pragma unroll
        for (int s = 16; s > 0; s >>= 1) {           // 32-lane segment reduce
            dot += __shfl_xor(dot, s);
            ss  += __shfl_xor(ss, s);
        }
        float sim = dot / fmaxf(sqrtf(ss), 1e-12f);
#pragma unroll
        for (int q = 0; q < 2; ++q) {
            float sq = __shfl(sim, q * 32);          // wave-uniform
            if (sq > v[15]) {
                float cv = sq; int ci = G * SUBROWS + 2 * w + q;
#pragma unroll
                for (int jj = 0; jj < 16; ++jj) {
                    if (cv > v[jj]) {
                        float tv = v[jj]; int ti = id[jj];
                        v[jj] = cv; id[jj] = ci; cv = tv; ci = ti;
                    }
                }
            }
        }
    };

    // ---- prologue: stage seq positions 0,1,2 into slots 0,1,2 -------------
    {
        int se = s0;
        stage(bid + se * NBLKS, 0);
        se = (se + 1 >= ns) ? 0 : se + 1;
        stage(bid + se * NBLKS, 1);
        se = (se + 1 >= ns) ? 0 : se + 1;
        stage(bid + se * NBLKS, 2);
    }

    // loop-carried wrapped indices: scur = seq pos s, spre = seq pos s+3
    int scur = s0;
    int spre = s0 + 3; if (spre >= ns) spre -= ns;

#pragma unroll 1
    for (int s = 0; s < ns; ++s) {
        stage(bid + spre * NBLKS, (s + 3) & 3);      // unconditional (wraps)
        spre = (spre + 1 >= ns) ? 0 : spre + 1;
        asm volatile("s_waitcnt vmcnt(12)" ::: "memory");
        __builtin_amdgcn_sched_barrier(0);
        compute(bid + scur * NBLKS, s & 3);
        __builtin_amdgcn_sched_barrier(0);
        scur = (scur + 1 >= ns) ? 0 : scur + 1;
    }

    asm volatile("s_waitcnt vmcnt(0)" ::: "memory"); // drain DMA before exit path

    // ---- merge 4 waves' top-16 -> block top-16 (separate scratch) ---------
    if (lane == 0) {
#pragma unroll
        for (int j = 0; j < 16; ++j) { bv[w * 16 + j] = v[j]; bi[w * 16 + j] = id[j]; }
    }
    __syncthreads();
    if (w == 0) {
        float lv = bv[lane]; int li = bi[lane];
        for (int rr = 0; rr < NRET; ++rr) {
            float mv = lv; int mi = li;
#pragma unroll
            for (int s = 32; s > 0; s >>= 1) {
                float ov = __shfl_xor(mv, s); int oi = __shfl_xor(mi, s);
                if (ov > mv || (ov == mv && oi < mi)) { mv = ov; mi = oi; }
            }
            if (lane == 0) {
                cand_v[bid * NRET + rr] = mv;
                cand_i[bid * NRET + rr] = mi;
            }
            if (lv == mv && li == mi) { lv = -FLT_MAX; li = 0x7fffffff; }
        }
    }
}

// ---------------- Kernel 3: final top-16 + softmax + gather ----------------
__global__ __launch_bounds__(256) void merge_out(
        const float* __restrict__ cand_v, const int* __restrict__ cand_i,
        const float* __restrict__ values, float* __restrict__ out) {
    const int tid  = threadIdx.x;
    const int wid  = tid >> 6;
    const int lane = tid & 63;
    const int M4 = (NBLKS * NRET) / 4;           // 2048 float4 groups

    float v[16]; int id[16];
#pragma unroll
    for (int j = 0; j < 16; ++j) { v[j] = -FLT_MAX; id[j] = 0x7fffffff; }

    const float4* cv4 = (const float4*)cand_v;
    const int4*   ci4 = (const int4*)cand_i;
    for (int c = tid; c < M4; c += 256) {        // 8 iterations
        float4 cv = cv4[c]; int4 ci = ci4[c];
        float cvs[4] = {cv.x, cv.y, cv.z, cv.w};
        int   cis[4] = {ci.x, ci.y, ci.z, ci.w};
#pragma unroll
        for (int u = 0; u < 4; ++u) {
            float cu = cvs[u]; int iu = cis[u];
            if (cu > v[15]) {
#pragma unroll
                for (int j = 0; j < 16; ++j) {
                    if (cu > v[j]) {
                        float tv = v[j]; int ti = id[j];
                        v[j] = cu; id[j] = iu; cu = tv; iu = ti;
                    }
                }
            }
        }
    }

    __shared__ float sv[64];
    __shared__ int   si[64];
    for (int rr = 0; rr < NRET; ++rr) {
        float mv = v[0]; int mi = id[0];
#pragma unroll
        for (int s = 32; s > 0; s >>= 1) {
            float ov = __shfl_xor(mv, s); int oi = __shfl_xor(mi, s);
            if (ov > mv || (ov == mv && oi < mi)) { mv = ov; mi = oi; }
        }
        if (v[0] == mv && id[0] == mi) {
#pragma unroll
            for (int j = 0; j < 15; ++j) { v[j] = v[j + 1]; id[j] = id[j + 1]; }
            v[15] = -FLT_MAX; id[15] = 0x7fffffff;
        }
        if (lane == 0) { sv[wid * 16 + rr] = mv; si[wid * 16 + rr] = mi; }
    }
    __syncthreads();

    if (wid == 0) {
        float lv = sv[lane]; int li = si[lane];
        float sel_v = -FLT_MAX; int sel_i = 0;
        for (int rr = 0; rr < NRET; ++rr) {
            float mv = lv; int mi = li;
#pragma unroll
            for (int s = 32; s > 0; s >>= 1) {
                float ov = __shfl_xor(mv, s); int oi = __shfl_xor(mi, s);
                if (ov > mv || (ov == mv && oi < mi)) { mv = ov; mi = oi; }
            }
            if (lv == mv && li == mi) { lv = -FLT_MAX; li = 0x7fffffff; }
            if (lane == rr) { sel_v = mv; sel_i = mi; }
        }

        // softmax over the 16 (lane 0 holds the max: rounds are descending)
        float m0 = __shfl(sel_v, 0);
        float e = (lane < NRET) ? expf(sel_v - m0) : 0.0f;
        float denom = wave_sum(e);

        float acc0 = 0.f, acc1 = 0.f;
        for (int rr = 0; rr < NRET; ++rr) {
            float ar = __shfl(e, rr) / denom;
            int   ir = __shfl(sel_i, rr);
            const float* vr = values + (size_t)ir * VALUE_DIM;
            acc0 += ar * vr[lane];
            acc1 += ar * vr[lane + 64];
        }
        out[lane]      = acc0;
        out[lane + 64] = acc1;
    }
}

extern "C" void kernel_launch(void* const* d_in, const int* in_sizes, int n_in,
                              void* d_out, int out_size, void* d_ws, size_t ws_size,
                              hipStream_t stream) {
    const float* query  = (const float*)d_in[0];
    const float* W1     = (const float*)d_in[1];
    const float* b1     = (const float*)d_in[2];
    const float* W2     = (const float*)d_in[3];
    const float* b2     = (const float*)d_in[4];
    const float* gamma  = (const float*)d_in[5];
    const float* beta   = (const float*)d_in[6];
    const float* keys   = (const float*)d_in[7];
    const float* values = (const float*)d_in[8];
    float* out = (float*)d_out;

    float* ws = (float*)d_ws;
    float* h1     = ws;                  // 512
    float* h2     = ws + 512;            // 512
    float* qn     = ws + 1024;           // 512
    float* cand_v = ws + 2048;           // NBLKS*16 floats
    int*   cand_i = (int*)(ws + 2048 + NBLKS * NRET);

    matvec512<true ><<<128, 256, 0, stream>>>(W1, query, b1, h1);
    matvec512<false><<<128, 256, 0, stream>>>(W2, h1, b2, h2);
    ln_l2norm<<<1, 512, 0, stream>>>(h2, gamma, beta, qn);
    sim_topk<<<NBLKS, 256, 0, stream>>>(keys, qn, cand_v, cand_i);
    merge_out<<<1, 256, 0, stream>>>(cand_v, cand_i, values, out);
}